// Round 6
// baseline (351.501 us; speedup 1.0000x reference)
//
#include <hip/hip_runtime.h>

namespace {

constexpr int BD = 2;
constexpr int DD = 160, HH = 192, WW = 224;
constexpr float INV_WIN = 1.0f / 729.0f;
constexpr float EPSV = 1e-5f;

constexpr int TH = 16, TW = 16;          // output tile (H x W)
constexpr int DC = 16;                   // output planes per d-chunk
constexpr int NREAL = DC + 8;            // 24 plane steps (exactly 12 supersteps)
constexpr int NSS = NREAL / 2;           // 12, FULLY UNROLLED
constexpr int NCH = DD / DC;             // 10
constexpr int GX = WW / TW;              // 14
constexpr int GY = HH / TH;              // 12
constexpr int GZ = BD * NCH;             // 20
constexpr int NBLK = GX * GY * GZ;       // 3360
constexpr double NTOT = (double)BD * DD * HH * WW;

// srow: [plane][field][w*24 + row], rows 0..23 contiguous.
// SR_FS = 388 (=16*24+4; /4=97 == 1 mod 8). Bank audit: S2 b128 writes and
// S3 b128 reads are exactly 8 lanes/bank-quad in every wave = conflict-free.
constexpr int SR_FS = 388;
constexpr int SR_PL = 5 * SR_FS;         // 1940
// scol: [plane][field][w*20 + o], o 0..15 contiguous.
// SC_FS = 324 (=16*20+4; /4=81 == 1 mod 8). S3 b128 writes uniform 8/quad;
// S4 b32 reads exactly 2/bank (free).
constexpr int SC_FS = 324;
constexpr int SC_PL = 5 * SC_FS;         // 1620

} // namespace

typedef float f4u __attribute__((ext_vector_type(4), aligned(4)));  // 4B-aligned vec load

__global__ __launch_bounds__(256)
void ncc_fused(const float* __restrict__ x, const float* __restrict__ y,
               float* __restrict__ bsum) {
  const int tid = threadIdx.x;
  const int w0 = blockIdx.x * TW;
  const int h0 = blockIdx.y * TH;
  const int zb = blockIdx.z;
  const int b  = zb / NCH;
  const int d0 = (zb - b * NCH) * DC;

  __shared__ __align__(16) float srowF[2 * SR_PL];   // 15520 B
  __shared__ __align__(16) float scolF[2 * SC_PL];   // 12960 B
  __shared__ float swsum[4];

  // ---- S2 roles: 192 threads = 2 planes x 6 row-quads x 16 w-columns.
  // Thread owns output column wl, input rows 4rq..4rq+3 of its plane.
  const bool s2a = tid < 192;
  const int p2  = tid / 96;
  const int t96 = tid - 96 * p2;
  const int rq  = t96 >> 4;            // 0..5
  const int wl  = t96 & 15;            // output w lane
  const int gwb = w0 + wl - 4;         // 9-wide window base (any dword align)
  const bool fastw = (gwb >= 0) && (gwb + 8 < WW);
  const int gh0 = h0 - 4 + rq * 4;
  int roff[4]; bool rok[4];
#pragma unroll
  for (int k = 0; k < 4; ++k) {
    const int gh = gh0 + k;
    rok[k]  = (unsigned)gh < (unsigned)HH;
    roff[k] = gh * WW + gwb;           // only used when rok
  }
  const unsigned plane = (unsigned)HH * WW;

  const int ow = tid & 15;
  const int oh = tid >> 4;

  // D-ring: 9 slots x 5 fields; slot indices static after full unroll.
  float rg0[9], rg1[9], rg2[9], rg3[9], rg4[9];
#pragma unroll
  for (int k = 0; k < 9; ++k) { rg0[k]=0.f; rg1[k]=0.f; rg2[k]=0.f; rg3[k]=0.f; rg4[k]=0.f; }
  float a0=0.f, a1=0.f, a2=0.f, a3=0.f, a4=0.f;
  float lsum = 0.0f;

#pragma unroll
  for (int ss = 0; ss < NSS; ++ss) {
    const int sA = 2 * ss;
    const int sB = sA + 1;
    const int slA = sA % 9;
    const int slB = sB % 9;

    // ---- S2': W-sums for 4 rows x 5 fields at one w, straight from global.
    if (s2a) {
      const int s   = sA + p2;
      const int din = d0 - 4 + s;
      const bool dok = (din >= 0) && (din < DD);
      const float* xp = x + (size_t)((unsigned)b * DD + (unsigned)(dok ? din : 0)) * plane;
      const float* yp = y + (size_t)((unsigned)b * DD + (unsigned)(dok ? din : 0)) * plane;
      float q0[4], q1[4], q2[4], q3[4], q4[4];
#pragma unroll
      for (int k = 0; k < 4; ++k) {
        float xv[9], yv[9];
        const bool ok = dok && rok[k];
        if (ok && fastw) {
          const float* px = xp + roff[k];
          const float* py = yp + roff[k];
          const f4u xa = *(const f4u*)px;
          const f4u xb = *(const f4u*)(px + 4);
          const f4u ya = *(const f4u*)py;
          const f4u yb = *(const f4u*)(py + 4);
#pragma unroll
          for (int e = 0; e < 4; ++e) { xv[e] = xa[e]; xv[e+4] = xb[e]; yv[e] = ya[e]; yv[e+4] = yb[e]; }
          xv[8] = px[8]; yv[8] = py[8];
        } else if (ok) {
#pragma unroll
          for (int e = 0; e < 9; ++e) {
            const int gw = gwb + e;
            const bool in = (unsigned)gw < (unsigned)WW;
            xv[e] = in ? xp[roff[k] + e] : 0.0f;
            yv[e] = in ? yp[roff[k] + e] : 0.0f;
          }
        } else {
#pragma unroll
          for (int e = 0; e < 9; ++e) { xv[e] = 0.0f; yv[e] = 0.0f; }
        }
        float s0=0.f, s1=0.f, s2=0.f, s3=0.f, s4=0.f;
#pragma unroll
        for (int t = 0; t < 9; ++t) {
          s0 += xv[t]; s1 += yv[t];
          s2 = fmaf(xv[t], xv[t], s2);
          s3 = fmaf(yv[t], yv[t], s3);
          s4 = fmaf(xv[t], yv[t], s4);
        }
        q0[k]=s0; q1[k]=s1; q2[k]=s2; q3[k]=s3; q4[k]=s4;
      }
      const int wb = p2 * SR_PL + wl * 24 + rq * 4;
      *(float4*)&srowF[wb + 0 * SR_FS] = make_float4(q0[0], q0[1], q0[2], q0[3]);
      *(float4*)&srowF[wb + 1 * SR_FS] = make_float4(q1[0], q1[1], q1[2], q1[3]);
      *(float4*)&srowF[wb + 2 * SR_FS] = make_float4(q2[0], q2[1], q2[2], q2[3]);
      *(float4*)&srowF[wb + 3 * SR_FS] = make_float4(q3[0], q3[1], q3[2], q3[3]);
      *(float4*)&srowF[wb + 4 * SR_FS] = make_float4(q4[0], q4[1], q4[2], q4[3]);
    }
    __syncthreads();   // B: srow visible

    // ---- S3': H-sums; 160 threads = 2 planes x 5 fields x 16 w.
    // Reads 24 contiguous rows (6 b128), emits all 16 outputs via running sum.
    if (tid < 160) {
      const int p3  = tid / 80;
      const int r3  = tid - 80 * p3;
      const int f3  = r3 >> 4;
      const int wl3 = r3 & 15;
      const float* rp = &srowF[p3 * SR_PL + f3 * SR_FS + wl3 * 24];
      float rv[24];
#pragma unroll
      for (int t = 0; t < 6; ++t) *(float4*)&rv[4 * t] = *(const float4*)&rp[4 * t];
      float acc = rv[0];
#pragma unroll
      for (int t = 1; t < 9; ++t) acc += rv[t];
      float ov[16];
      ov[0] = acc;
#pragma unroll
      for (int o = 1; o < 16; ++o) { acc += rv[o + 8] - rv[o - 1]; ov[o] = acc; }
      float* cp = &scolF[p3 * SC_PL + f3 * SC_FS + wl3 * 20];
#pragma unroll
      for (int t = 0; t < 4; ++t)
        *(float4*)&cp[4 * t] = make_float4(ov[4*t], ov[4*t+1], ov[4*t+2], ov[4*t+3]);
    }
    __syncthreads();   // C: scol visible

    // ---- S4: ring update for both planes + emit (all 256 threads)
    const float* cA = &scolF[ow * 20 + oh];
    const float* cB = cA + SC_PL;
    const float gA0 = cA[0*SC_FS], gA1 = cA[1*SC_FS], gA2 = cA[2*SC_FS],
                gA3 = cA[3*SC_FS], gA4 = cA[4*SC_FS];
    const float gB0 = cB[0*SC_FS], gB1 = cB[1*SC_FS], gB2 = cB[2*SC_FS],
                gB3 = cB[3*SC_FS], gB4 = cB[4*SC_FS];

    a0 += gA0 - rg0[slA]; rg0[slA] = gA0;
    a1 += gA1 - rg1[slA]; rg1[slA] = gA1;
    a2 += gA2 - rg2[slA]; rg2[slA] = gA2;
    a3 += gA3 - rg3[slA]; rg3[slA] = gA3;
    a4 += gA4 - rg4[slA]; rg4[slA] = gA4;
    if (sA >= 8) {
      const float cross = fmaf(-a0 * INV_WIN, a1, a4);
      const float iv = fmaxf(fmaf(-a0 * INV_WIN, a0, a2), EPSV);
      const float jv = fmaxf(fmaf(-a1 * INV_WIN, a1, a3), EPSV);
      lsum += (cross * cross) / (iv * jv);
    }
    a0 += gB0 - rg0[slB]; rg0[slB] = gB0;
    a1 += gB1 - rg1[slB]; rg1[slB] = gB1;
    a2 += gB2 - rg2[slB]; rg2[slB] = gB2;
    a3 += gB3 - rg3[slB]; rg3[slB] = gB3;
    a4 += gB4 - rg4[slB]; rg4[slB] = gB4;
    if (sB >= 8) {
      const float cross = fmaf(-a0 * INV_WIN, a1, a4);
      const float iv = fmaxf(fmaf(-a0 * INV_WIN, a0, a2), EPSV);
      const float jv = fmaxf(fmaf(-a1 * INV_WIN, a1, a3), EPSV);
      lsum += (cross * cross) / (iv * jv);
    }
    // WAR safety: srow(ss+1) writes occur after all threads pass C(ss);
    // S3'(ss) srow reads finish before C(ss). scol(ss) S4-reads finish
    // before B(ss+1), and scol(ss+1) writes occur after B(ss+1).
  }

  // ---- block reduction
#pragma unroll
  for (int off = 32; off > 0; off >>= 1) lsum += __shfl_down(lsum, off);
  if ((tid & 63) == 0) swsum[tid >> 6] = lsum;
  __syncthreads();
  if (tid == 0) {
    const int bid = ((int)blockIdx.z * GY + (int)blockIdx.y) * GX + (int)blockIdx.x;
    bsum[bid] = swsum[0] + swsum[1] + swsum[2] + swsum[3];
  }
}

__global__ __launch_bounds__(256)
void ncc_finalize(const float* __restrict__ bsum, float* __restrict__ out) {
  double s = 0.0;
  for (int i = threadIdx.x; i < NBLK; i += 256) s += (double)bsum[i];
#pragma unroll
  for (int off = 32; off > 0; off >>= 1) s += __shfl_down(s, off);
  __shared__ double sh[4];
  if ((threadIdx.x & 63) == 0) sh[threadIdx.x >> 6] = s;
  __syncthreads();
  if (threadIdx.x == 0)
    out[0] = (float)(-(sh[0] + sh[1] + sh[2] + sh[3]) / NTOT);
}

extern "C" void kernel_launch(void* const* d_in, const int* in_sizes, int n_in,
                              void* d_out, int out_size, void* d_ws, size_t ws_size,
                              hipStream_t stream) {
  const float* x = (const float*)d_in[0];
  const float* y = (const float*)d_in[1];
  float* bsum = (float*)d_ws;          // 3360 floats, fully rewritten every call
  float* out  = (float*)d_out;

  dim3 grid(GX, GY, GZ);
  ncc_fused<<<grid, dim3(256), 0, stream>>>(x, y, bsum);
  ncc_finalize<<<1, dim3(256), 0, stream>>>(bsum, out);
}

// Round 7
// 211.129 us; speedup vs baseline: 1.6649x; 1.6649x over previous
//
#include <hip/hip_runtime.h>

namespace {

constexpr int BD = 2;
constexpr int DD = 160, HH = 192, WW = 224;
constexpr float INV_WIN = 1.0f / 729.0f;
constexpr float EPSV = 1e-5f;

constexpr int TH = 16, TW = 16;          // output tile (H x W)
constexpr int DC = 16;                   // output planes per d-chunk
constexpr int NREAL = DC + 8;            // 24 plane steps = 12 supersteps
constexpr int NSS = NREAL / 2;           // FULLY UNROLLED
constexpr int NCH = DD / DC;             // 10
constexpr int GX = WW / TW;              // 14
constexpr int GY = HH / TH;              // 12
constexpr int GZ = BD * NCH;             // 20
constexpr int NBLK = GX * GY * GZ;       // 3360
constexpr double NTOT = (double)BD * DD * HH * WW;

// srow: [plane][field][w*28 + row], rows 0..23 contiguous (pad to 28).
// SR_FS=452 (16*28+4): b128-aligned (mod4), f-shift 113==1 mod 8.
// SR_PL=2280: ==8 mod 32 -> S2 scatter-write waves tile banks exactly 2/bank
// (audited per-wave incl. the plane-straddling waves). S3 b128 reads: 8/quad.
constexpr int SR_FS = 452;
constexpr int SR_PL = 2280;
// scol: [plane][field][w*20 + o]. SC_FS=324, SC_PL=1620.
// S3 b128 writes 8/quad uniform; S4 b32 reads exactly 2/bank.
constexpr int SC_FS = 324;
constexpr int SC_PL = 1620;

} // namespace

__global__ __launch_bounds__(256)
void ncc_fused(const float* __restrict__ x, const float* __restrict__ y,
               float* __restrict__ bsum) {
  const int tid = threadIdx.x;
  const int w0 = blockIdx.x * TW;
  const int h0 = blockIdx.y * TH;
  const int zb = blockIdx.z;
  const int b  = zb / NCH;
  const int d0 = (zb - b * NCH) * DC;

  __shared__ __align__(16) float srowF[2 * SR_PL];   // 18240 B
  __shared__ __align__(16) float scolF[2 * SC_PL];   // 12960 B
  __shared__ float swsum[4];

  // ---- S2 roles: 192 threads = 2 planes x 24 rows x 4 col-segments,
  // each computing 4 sliding W-sums from a 12-wide register window.
  const bool s2a = tid < 192;
  const int p2  = tid / 96;
  const int t96 = tid - 96 * p2;
  const int r2  = t96 >> 2;            // input row 0..23
  const int seg = tid & 3;
  const int gh  = h0 - 4 + r2;
  const int gw0 = w0 - 4 + seg * 4;    // 16B aligned
  const bool hok = (unsigned)gh < (unsigned)HH;
  const bool fastw = (gw0 >= 0) && (gw0 + 11 < WW);
  const unsigned plane = (unsigned)HH * WW;

  auto prefetch = [&](int s, float4* vx, float4* vy) {
    const int din = d0 - 4 + s;
    const float4 z = make_float4(0.f, 0.f, 0.f, 0.f);
    vx[0] = vx[1] = vx[2] = z;
    vy[0] = vy[1] = vy[2] = z;
    if (s2a && hok && (s < NREAL) && (din >= 0) && (din < DD)) {
      const unsigned rb = ((unsigned)b * DD + (unsigned)din) * plane + (unsigned)gh * WW;
      if (fastw) {
        const float4* px = (const float4*)(x + rb + gw0);
        const float4* py = (const float4*)(y + rb + gw0);
        vx[0] = px[0]; vx[1] = px[1]; vx[2] = px[2];
        vy[0] = py[0]; vy[1] = py[1]; vy[2] = py[2];
      } else {
        float* fx = (float*)vx;
        float* fy = (float*)vy;
#pragma unroll
        for (int e = 0; e < 12; ++e) {
          const int gw = gw0 + e;
          if ((unsigned)gw < (unsigned)WW) {
            fx[e] = x[rb + gw];
            fy[e] = y[rb + gw];
          }
        }
      }
    }
  };

  const int ow = tid & 15;
  const int oh = tid >> 4;

  // D-ring: 9 slots x 5 fields; slot indices static after full unroll.
  float rg0[9], rg1[9], rg2[9], rg3[9], rg4[9];
#pragma unroll
  for (int k = 0; k < 9; ++k) { rg0[k]=0.f; rg1[k]=0.f; rg2[k]=0.f; rg3[k]=0.f; rg4[k]=0.f; }
  float a0=0.f, a1=0.f, a2=0.f, a3=0.f, a4=0.f;
  float lsum = 0.0f;

  float4 px4[3], py4[3];
  prefetch(p2, px4, py4);               // planes 0 (p2=0) and 1 (p2=1)

#pragma unroll
  for (int ss = 0; ss < NSS; ++ss) {
    const int sA = 2 * ss;
    const int sB = sA + 1;
    const int slA = sA % 9;
    const int slB = sB % 9;

    // issue next superstep's plane loads early (hidden behind S2-S4 + 2 barriers)
    float4 nx4[3], ny4[3];
    prefetch(2 * (ss + 1) + p2, nx4, ny4);

    // ---- S2: 12-wide register window -> 4 sliding 9-tap W-sums x 5 fields
    if (s2a) {
      float xv[12], yv[12];
#pragma unroll
      for (int k = 0; k < 3; ++k) {
        *(float4*)&xv[4 * k] = px4[k];
        *(float4*)&yv[4 * k] = py4[k];
      }
      float s0=0.f, s1=0.f, s2=0.f, s3=0.f, s4=0.f;
#pragma unroll
      for (int k = 0; k < 9; ++k) {
        s0 += xv[k]; s1 += yv[k];
        s2 = fmaf(xv[k], xv[k], s2);
        s3 = fmaf(yv[k], yv[k], s3);
        s4 = fmaf(xv[k], yv[k], s4);
      }
      // write w-sum for w = 4*seg + t at [f][w*28 + r2], t=0 then slide
      float* wb = &srowF[p2 * SR_PL + (seg * 4) * 28 + r2];
      wb[0 * SR_FS] = s0; wb[1 * SR_FS] = s1; wb[2 * SR_FS] = s2;
      wb[3 * SR_FS] = s3; wb[4 * SR_FS] = s4;
#pragma unroll
      for (int t = 1; t < 4; ++t) {
        const float xn = xv[8 + t], xo = xv[t - 1];
        const float yn = yv[8 + t], yo = yv[t - 1];
        s0 += xn - xo;
        s1 += yn - yo;
        s2 += fmaf(xn, xn, -(xo * xo));
        s3 += fmaf(yn, yn, -(yo * yo));
        s4 += fmaf(xn, yn, -(xo * yo));
        float* wt = wb + t * 28;
        wt[0 * SR_FS] = s0; wt[1 * SR_FS] = s1; wt[2 * SR_FS] = s2;
        wt[3 * SR_FS] = s3; wt[4 * SR_FS] = s4;
      }
    }
    __syncthreads();   // B: srow visible

    // ---- S3: H-sums; 160 thr = 2 planes x 5 fields x 16 w.
    // 6 contiguous b128 reads -> all 16 outputs via running sum -> 4 b128 writes.
    if (tid < 160) {
      const int p3  = tid / 80;
      const int r3  = tid - 80 * p3;
      const int f3  = r3 >> 4;
      const int wl3 = r3 & 15;
      const float* rp = &srowF[p3 * SR_PL + f3 * SR_FS + wl3 * 28];
      float rv[24];
#pragma unroll
      for (int t = 0; t < 6; ++t) *(float4*)&rv[4 * t] = *(const float4*)&rp[4 * t];
      float acc = rv[0];
#pragma unroll
      for (int t = 1; t < 9; ++t) acc += rv[t];
      float ov[16];
      ov[0] = acc;
#pragma unroll
      for (int o = 1; o < 16; ++o) { acc += rv[o + 8] - rv[o - 1]; ov[o] = acc; }
      float* cp = &scolF[p3 * SC_PL + f3 * SC_FS + wl3 * 20];
#pragma unroll
      for (int t = 0; t < 4; ++t)
        *(float4*)&cp[4 * t] = make_float4(ov[4*t], ov[4*t+1], ov[4*t+2], ov[4*t+3]);
    }
    __syncthreads();   // C: scol visible

    // ---- S4: ring update for both planes + emit (all 256 threads)
    const float* cA = &scolF[ow * 20 + oh];
    const float* cB = cA + SC_PL;
    const float gA0 = cA[0*SC_FS], gA1 = cA[1*SC_FS], gA2 = cA[2*SC_FS],
                gA3 = cA[3*SC_FS], gA4 = cA[4*SC_FS];
    const float gB0 = cB[0*SC_FS], gB1 = cB[1*SC_FS], gB2 = cB[2*SC_FS],
                gB3 = cB[3*SC_FS], gB4 = cB[4*SC_FS];

    a0 += gA0 - rg0[slA]; rg0[slA] = gA0;
    a1 += gA1 - rg1[slA]; rg1[slA] = gA1;
    a2 += gA2 - rg2[slA]; rg2[slA] = gA2;
    a3 += gA3 - rg3[slA]; rg3[slA] = gA3;
    a4 += gA4 - rg4[slA]; rg4[slA] = gA4;
    if (sA >= 8) {
      const float cross = fmaf(-a0 * INV_WIN, a1, a4);
      const float iv = fmaxf(fmaf(-a0 * INV_WIN, a0, a2), EPSV);
      const float jv = fmaxf(fmaf(-a1 * INV_WIN, a1, a3), EPSV);
      lsum += (cross * cross) / (iv * jv);
    }
    a0 += gB0 - rg0[slB]; rg0[slB] = gB0;
    a1 += gB1 - rg1[slB]; rg1[slB] = gB1;
    a2 += gB2 - rg2[slB]; rg2[slB] = gB2;
    a3 += gB3 - rg3[slB]; rg3[slB] = gB3;
    a4 += gB4 - rg4[slB]; rg4[slB] = gB4;
    if (sB >= 8) {
      const float cross = fmaf(-a0 * INV_WIN, a1, a4);
      const float iv = fmaxf(fmaf(-a0 * INV_WIN, a0, a2), EPSV);
      const float jv = fmaxf(fmaf(-a1 * INV_WIN, a1, a3), EPSV);
      lsum += (cross * cross) / (iv * jv);
    }

    // WAR safety: srow(ss+1) writes occur after all threads pass C(ss);
    // S3(ss) srow reads finish before C(ss); scol(ss) S4-reads finish
    // before B(ss+1); scol(ss+1) writes occur after B(ss+1).
#pragma unroll
    for (int k = 0; k < 3; ++k) { px4[k] = nx4[k]; py4[k] = ny4[k]; }
  }

  // ---- block reduction
#pragma unroll
  for (int off = 32; off > 0; off >>= 1) lsum += __shfl_down(lsum, off);
  if ((tid & 63) == 0) swsum[tid >> 6] = lsum;
  __syncthreads();
  if (tid == 0) {
    const int bid = ((int)blockIdx.z * GY + (int)blockIdx.y) * GX + (int)blockIdx.x;
    bsum[bid] = swsum[0] + swsum[1] + swsum[2] + swsum[3];
  }
}

__global__ __launch_bounds__(256)
void ncc_finalize(const float* __restrict__ bsum, float* __restrict__ out) {
  double s = 0.0;
  for (int i = threadIdx.x; i < NBLK; i += 256) s += (double)bsum[i];
#pragma unroll
  for (int off = 32; off > 0; off >>= 1) s += __shfl_down(s, off);
  __shared__ double sh[4];
  if ((threadIdx.x & 63) == 0) sh[threadIdx.x >> 6] = s;
  __syncthreads();
  if (threadIdx.x == 0)
    out[0] = (float)(-(sh[0] + sh[1] + sh[2] + sh[3]) / NTOT);
}

extern "C" void kernel_launch(void* const* d_in, const int* in_sizes, int n_in,
                              void* d_out, int out_size, void* d_ws, size_t ws_size,
                              hipStream_t stream) {
  const float* x = (const float*)d_in[0];
  const float* y = (const float*)d_in[1];
  float* bsum = (float*)d_ws;          // 3360 floats, fully rewritten every call
  float* out  = (float*)d_out;

  dim3 grid(GX, GY, GZ);
  ncc_fused<<<grid, dim3(256), 0, stream>>>(x, y, bsum);
  ncc_finalize<<<1, dim3(256), 0, stream>>>(bsum, out);
}

// Round 8
// 208.048 us; speedup vs baseline: 1.6895x; 1.0148x over previous
//
#include <hip/hip_runtime.h>

namespace {

constexpr int BD = 2;
constexpr int DD = 160, HH = 192, WW = 224;
constexpr float INV_WIN = 1.0f / 729.0f;
constexpr float EPSV = 1e-5f;

constexpr int TH = 16, TW = 16;          // output tile (H x W)
constexpr int DC = 16;                   // output planes per d-chunk
constexpr int NREAL = DC + 8;            // 24 plane steps = 12 pairs
constexpr int NPAIR = NREAL / 2;         // 12; superstep loop runs 13 (pipelined)
constexpr int NCH = DD / DC;             // 10
constexpr int GX = WW / TW;              // 14
constexpr int GY = HH / TH;              // 12
constexpr int GZ = BD * NCH;             // 20
constexpr int NBLK = GX * GY * GZ;       // 3360
constexpr double NTOT = (double)BD * DD * HH * WW;

// srow: [buf][plane][field][w*28 + row], rows 0..23 contiguous (pad 28).
// SR_FS=452 (f-shift /4=113==1 mod 8), SR_PL=2280 (==8 mod 32). Audited:
// S2 b32 scatter 2/bank; S3 b128 reads uniform /quad (incl. straddle waves).
// Pair-buffer stride 2*SR_PL=4560 (==16 mod 32) is wave-uniform -> no effect.
constexpr int SR_FS = 452;
constexpr int SR_PL = 2280;
// scol: [plane][field][w*20 + o]. SC_FS=324, SC_PL=1620. S3 b128 writes
// uniform /quad; S4 b32 reads exactly 2/bank.
constexpr int SC_FS = 324;
constexpr int SC_PL = 1620;

} // namespace

__global__ __launch_bounds__(256)
void ncc_fused(const float* __restrict__ x, const float* __restrict__ y,
               float* __restrict__ bsum) {
  const int tid = threadIdx.x;
  const int w0 = blockIdx.x * TW;
  const int h0 = blockIdx.y * TH;
  const int zb = blockIdx.z;
  const int b  = zb / NCH;
  const int d0 = (zb - b * NCH) * DC;

  __shared__ __align__(16) float srowF[2][2 * SR_PL];  // 36480 B (pair dbuf)
  __shared__ __align__(16) float scolF[2 * SC_PL];     // 12960 B
  __shared__ float swsum[4];

  // ---- S2 roles: tids 0..191 = 2 planes x 24 rows x 4 col-segments,
  // 12-wide register window -> 4 sliding 9-tap W-sums x 5 fields.
  const bool s2a = tid < 192;
  const int p2  = tid / 96;
  const int t96 = tid - 96 * p2;
  const int r2  = t96 >> 2;            // input row 0..23
  const int seg = tid & 3;
  const int gh  = h0 - 4 + r2;
  const int gw0 = w0 - 4 + seg * 4;    // 16B aligned
  const bool hok = (unsigned)gh < (unsigned)HH;
  const bool fastw = (gw0 >= 0) && (gw0 + 11 < WW);
  const unsigned plane = (unsigned)HH * WW;

  auto prefetch = [&](int s, float4* vx, float4* vy) {
    const int din = d0 - 4 + s;
    const float4 z = make_float4(0.f, 0.f, 0.f, 0.f);
    vx[0] = vx[1] = vx[2] = z;
    vy[0] = vy[1] = vy[2] = z;
    if (s2a && hok && (s < NREAL) && (din >= 0) && (din < DD)) {
      const unsigned rb = ((unsigned)b * DD + (unsigned)din) * plane + (unsigned)gh * WW;
      if (fastw) {
        const float4* px = (const float4*)(x + rb + gw0);
        const float4* py = (const float4*)(y + rb + gw0);
        vx[0] = px[0]; vx[1] = px[1]; vx[2] = px[2];
        vy[0] = py[0]; vy[1] = py[1]; vy[2] = py[2];
      } else {
        float* fx = (float*)vx;
        float* fy = (float*)vy;
#pragma unroll
        for (int e = 0; e < 12; ++e) {
          const int gw = gw0 + e;
          if ((unsigned)gw < (unsigned)WW) {
            fx[e] = x[rb + gw];
            fy[e] = y[rb + gw];
          }
        }
      }
    }
  };

  // ---- S3 roles: tids 96..255 = 2 planes x 5 fields x 16 w (wave balance:
  // wave0 S2-only, wave3 S3-only, waves1-2 mixed).
  const int t3  = tid - 96;
  const int p3  = t3 / 80;
  const int r3  = t3 - 80 * p3;
  const int f3  = r3 >> 4;
  const int wl3 = r3 & 15;

  const int ow = tid & 15;
  const int oh = tid >> 4;

  // D-ring: 9 slots x 5 fields; slot indices static after full unroll.
  float rg0[9], rg1[9], rg2[9], rg3[9], rg4[9];
#pragma unroll
  for (int k = 0; k < 9; ++k) { rg0[k]=0.f; rg1[k]=0.f; rg2[k]=0.f; rg3[k]=0.f; rg4[k]=0.f; }
  float a0=0.f, a1=0.f, a2=0.f, a3=0.f, a4=0.f;
  float lsum = 0.0f;

  float4 px4[3], py4[3];
  prefetch(p2, px4, py4);               // pair 0

  // Pipelined supersteps: S2 stages pair ss; S3/S4 consume pair ss-1.
#pragma unroll
  for (int ss = 0; ss <= NPAIR; ++ss) {
    // prefetch pair ss+1 (consumed by S2 next superstep)
    float4 nx4[3], ny4[3];
    if (ss + 1 < NPAIR) prefetch(2 * (ss + 1) + p2, nx4, ny4);

    // ---- S2 (pair ss): W-sums -> srow[ss&1]. Independent of S3 below.
    if (ss < NPAIR && s2a) {
      float xv[12], yv[12];
#pragma unroll
      for (int k = 0; k < 3; ++k) {
        *(float4*)&xv[4 * k] = px4[k];
        *(float4*)&yv[4 * k] = py4[k];
      }
      float s0=0.f, s1=0.f, s2=0.f, s3=0.f, s4=0.f;
#pragma unroll
      for (int k = 0; k < 9; ++k) {
        s0 += xv[k]; s1 += yv[k];
        s2 = fmaf(xv[k], xv[k], s2);
        s3 = fmaf(yv[k], yv[k], s3);
        s4 = fmaf(xv[k], yv[k], s4);
      }
      float* wb = &srowF[ss & 1][p2 * SR_PL + (seg * 4) * 28 + r2];
      wb[0 * SR_FS] = s0; wb[1 * SR_FS] = s1; wb[2 * SR_FS] = s2;
      wb[3 * SR_FS] = s3; wb[4 * SR_FS] = s4;
#pragma unroll
      for (int t = 1; t < 4; ++t) {
        const float xn = xv[8 + t], xo = xv[t - 1];
        const float yn = yv[8 + t], yo = yv[t - 1];
        s0 += xn - xo;
        s1 += yn - yo;
        s2 += fmaf(xn, xn, -(xo * xo));
        s3 += fmaf(yn, yn, -(yo * yo));
        s4 += fmaf(xn, yn, -(xo * yo));
        float* wt = wb + t * 28;
        wt[0 * SR_FS] = s0; wt[1 * SR_FS] = s1; wt[2 * SR_FS] = s2;
        wt[3 * SR_FS] = s3; wt[4 * SR_FS] = s4;
      }
    }

    // ---- S3 (pair ss-1): H-sums from srow[(ss-1)&1] -> scol.
    // No barrier needed vs S2: different srow buffer (written last superstep,
    // separated by barrier E(ss-1)).
    if (ss >= 1 && tid >= 96) {
      const float* rp = &srowF[(ss - 1) & 1][p3 * SR_PL + f3 * SR_FS + wl3 * 28];
      float rv[24];
#pragma unroll
      for (int t = 0; t < 6; ++t) *(float4*)&rv[4 * t] = *(const float4*)&rp[4 * t];
      float acc = rv[0];
#pragma unroll
      for (int t = 1; t < 9; ++t) acc += rv[t];
      float ov[16];
      ov[0] = acc;
#pragma unroll
      for (int o = 1; o < 16; ++o) { acc += rv[o + 8] - rv[o - 1]; ov[o] = acc; }
      float* cp = &scolF[p3 * SC_PL + f3 * SC_FS + wl3 * 20];
#pragma unroll
      for (int t = 0; t < 4; ++t)
        *(float4*)&cp[4 * t] = make_float4(ov[4*t], ov[4*t+1], ov[4*t+2], ov[4*t+3]);
    }
    __syncthreads();   // C: scol visible (also orders S2 writes vs next S3)

    // ---- S4 (pair ss-1): ring update + emit (all 256 threads)
    if (ss >= 1) {
      const int ps  = ss - 1;
      const int sA  = 2 * ps;
      const int sB  = sA + 1;
      const int slA = sA % 9;
      const int slB = sB % 9;
      const float* cA = &scolF[ow * 20 + oh];
      const float* cB = cA + SC_PL;
      const float gA0 = cA[0*SC_FS], gA1 = cA[1*SC_FS], gA2 = cA[2*SC_FS],
                  gA3 = cA[3*SC_FS], gA4 = cA[4*SC_FS];
      const float gB0 = cB[0*SC_FS], gB1 = cB[1*SC_FS], gB2 = cB[2*SC_FS],
                  gB3 = cB[3*SC_FS], gB4 = cB[4*SC_FS];

      a0 += gA0 - rg0[slA]; rg0[slA] = gA0;
      a1 += gA1 - rg1[slA]; rg1[slA] = gA1;
      a2 += gA2 - rg2[slA]; rg2[slA] = gA2;
      a3 += gA3 - rg3[slA]; rg3[slA] = gA3;
      a4 += gA4 - rg4[slA]; rg4[slA] = gA4;
      if (sA >= 8) {
        const float cross = fmaf(-a0 * INV_WIN, a1, a4);
        const float iv = fmaxf(fmaf(-a0 * INV_WIN, a0, a2), EPSV);
        const float jv = fmaxf(fmaf(-a1 * INV_WIN, a1, a3), EPSV);
        lsum += (cross * cross) / (iv * jv);
      }
      a0 += gB0 - rg0[slB]; rg0[slB] = gB0;
      a1 += gB1 - rg1[slB]; rg1[slB] = gB1;
      a2 += gB2 - rg2[slB]; rg2[slB] = gB2;
      a3 += gB3 - rg3[slB]; rg3[slB] = gB3;
      a4 += gB4 - rg4[slB]; rg4[slB] = gB4;
      if (sB >= 8) {
        const float cross = fmaf(-a0 * INV_WIN, a1, a4);
        const float iv = fmaxf(fmaf(-a0 * INV_WIN, a0, a2), EPSV);
        const float jv = fmaxf(fmaf(-a1 * INV_WIN, a1, a3), EPSV);
        lsum += (cross * cross) / (iv * jv);
      }
    }
    __syncthreads();   // E: S4 scol-reads done before S3(ss+1) overwrites;
                       //    S2(ss) srow writes visible to S3(ss+1).
    if (ss + 1 < NPAIR) {
#pragma unroll
      for (int k = 0; k < 3; ++k) { px4[k] = nx4[k]; py4[k] = ny4[k]; }
    }
  }

  // ---- block reduction
#pragma unroll
  for (int off = 32; off > 0; off >>= 1) lsum += __shfl_down(lsum, off);
  if ((tid & 63) == 0) swsum[tid >> 6] = lsum;
  __syncthreads();
  if (tid == 0) {
    const int bid = ((int)blockIdx.z * GY + (int)blockIdx.y) * GX + (int)blockIdx.x;
    bsum[bid] = swsum[0] + swsum[1] + swsum[2] + swsum[3];
  }
}

__global__ __launch_bounds__(256)
void ncc_finalize(const float* __restrict__ bsum, float* __restrict__ out) {
  double s = 0.0;
  for (int i = threadIdx.x; i < NBLK; i += 256) s += (double)bsum[i];
#pragma unroll
  for (int off = 32; off > 0; off >>= 1) s += __shfl_down(s, off);
  __shared__ double sh[4];
  if ((threadIdx.x & 63) == 0) sh[threadIdx.x >> 6] = s;
  __syncthreads();
  if (threadIdx.x == 0)
    out[0] = (float)(-(sh[0] + sh[1] + sh[2] + sh[3]) / NTOT);
}

extern "C" void kernel_launch(void* const* d_in, const int* in_sizes, int n_in,
                              void* d_out, int out_size, void* d_ws, size_t ws_size,
                              hipStream_t stream) {
  const float* x = (const float*)d_in[0];
  const float* y = (const float*)d_in[1];
  float* bsum = (float*)d_ws;          // 3360 floats, fully rewritten every call
  float* out  = (float*)d_out;

  dim3 grid(GX, GY, GZ);
  ncc_fused<<<grid, dim3(256), 0, stream>>>(x, y, bsum);
  ncc_finalize<<<1, dim3(256), 0, stream>>>(bsum, out);
}